// Round 13
// baseline (268.596 us; speedup 1.0000x reference)
//
#include <hip/hip_runtime.h>
#include <math.h>

#define NH 16          // heads
#define HD 64          // head dim
#define NB 4           // batch
#define SQ 1024        // seq len
#define CH 1024        // channels

typedef __bf16   bf16x8 __attribute__((ext_vector_type(8)));
typedef __bf16   bf16x4 __attribute__((ext_vector_type(4)));
typedef _Float16 f16x8  __attribute__((ext_vector_type(8)));
typedef _Float16 f16x4  __attribute__((ext_vector_type(4)));
typedef float    f32x4  __attribute__((ext_vector_type(4)));

typedef const __attribute__((address_space(1))) void gvoid_t;
typedef __attribute__((address_space(3))) void lvoid_t;

// ---------- split fp32 -> bf16 hi/lo ----------
__global__ __launch_bounds__(256) void k_split(
    const float* __restrict__ in, __bf16* __restrict__ hi,
    __bf16* __restrict__ lo, int n4)
{
    const int idx = blockIdx.x * 256 + threadIdx.x;
    if (idx >= n4) return;
    const float4 v = ((const float4*)in)[idx];
    bf16x4 h, l;
    h[0] = (__bf16)v.x; l[0] = (__bf16)(v.x - (float)h[0]);
    h[1] = (__bf16)v.y; l[1] = (__bf16)(v.y - (float)h[1]);
    h[2] = (__bf16)v.z; l[2] = (__bf16)(v.z - (float)h[2]);
    h[3] = (__bf16)v.w; l[3] = (__bf16)(v.w - (float)h[3]);
    ((bf16x4*)hi)[idx] = h;
    ((bf16x4*)lo)[idx] = l;
}

// ---------- hi-only split (for x: 2-pass QKV GEMM needs no A_lo) ----------
__global__ __launch_bounds__(256) void k_split_hi(
    const float* __restrict__ in, __bf16* __restrict__ hi, int n4)
{
    const int idx = blockIdx.x * 256 + threadIdx.x;
    if (idx >= n4) return;
    const float4 v = ((const float4*)in)[idx];
    bf16x4 h;
    h[0] = (__bf16)v.x; h[1] = (__bf16)v.y;
    h[2] = (__bf16)v.z; h[3] = (__bf16)v.w;
    ((bf16x4*)hi)[idx] = h;
}

// ---------- split-bf16 MFMA GEMM: C = A @ B^T (+bias) ----------
// PASSES==3: acc += Ah*Bl + Al*Bh + Ah*Bh   (full split)
// PASSES==2: acc += Ah*Bl + Ah*Bh           (drop Al term; Al not staged)
template<int EPI, int PASSES>
__global__ __launch_bounds__(256) void k_mfma_gemm(
    const __bf16* __restrict__ Ah, const __bf16* __restrict__ Al,
    const __bf16* __restrict__ Bh, const __bf16* __restrict__ Bl,
    const float* __restrict__ bias, float* __restrict__ outp,
    _Float16* __restrict__ qf, _Float16* __restrict__ kf, _Float16* __restrict__ vTf,
    const float* __restrict__ qg, const float* __restrict__ qb_,
    const float* __restrict__ kg, const float* __restrict__ kb_)
{
    __shared__ __align__(16) __bf16 sAh[128 * 32];
    __shared__ __align__(16) __bf16 sAl[(PASSES == 3) ? 128 * 32 : 8];
    __shared__ __align__(16) __bf16 sBh[128 * 32];
    __shared__ __align__(16) __bf16 sBl[128 * 32];

    const int tid = threadIdx.x;
    const int wid = tid >> 6, lane = tid & 63;
    const int wr = wid >> 1, wc = wid & 1;
    const int m0 = blockIdx.y * 128, n0 = blockIdx.x * 128;

    f32x4 acc[4][4];
    #pragma unroll
    for (int i = 0; i < 4; ++i)
        #pragma unroll
        for (int j = 0; j < 4; ++j)
            acc[i][j] = (f32x4){0.f, 0.f, 0.f, 0.f};

    // staging assignment
    const __bf16* gsrc;
    __bf16* sdst;
    int nloads, ibase, gbase;
    if (PASSES == 3) {
        gsrc = (wid == 0) ? Ah : (wid == 1) ? Al : (wid == 2) ? Bh : Bl;
        sdst = (wid == 0) ? sAh : (wid == 1) ? sAl : (wid == 2) ? sBh : sBl;
        gbase = (wid < 2) ? m0 : n0;
        nloads = 8; ibase = 0;
    } else {
        gsrc = (wid == 1) ? Bh : (wid == 2) ? Bl : Ah;
        sdst = (wid == 1) ? sBh : (wid == 2) ? sBl : sAh;
        gbase = (wid == 1 || wid == 2) ? n0 : m0;
        nloads = (wid == 1 || wid == 2) ? 8 : 4;
        ibase = (wid == 3) ? 4 : 0;
    }
    const int grow = gbase + (lane >> 2);
    const int gcol = (lane & 3) * 8;

    const int arow = wr * 64 + (lane & 15);
    const int brow = wc * 64 + (lane & 15);
    const int koff = (lane >> 4) * 8;

    for (int k0 = 0; k0 < CH; k0 += 32) {
        for (int i = 0; i < nloads; ++i) {
            const __bf16* g = gsrc + (size_t)(grow + (ibase + i) * 16) * CH + k0 + gcol;
            __builtin_amdgcn_global_load_lds((gvoid_t*)g,
                                             (lvoid_t*)(sdst + (ibase + i) * 512),
                                             16, 0, 0);
        }
        __syncthreads();

        bf16x8 a_h[4], b_h[4], b_l[4];
        bf16x8 a_l[4];
        #pragma unroll
        for (int f = 0; f < 4; ++f) {
            a_h[f] = *(const bf16x8*)&sAh[(arow + f * 16) * 32 + koff];
            b_h[f] = *(const bf16x8*)&sBh[(brow + f * 16) * 32 + koff];
            b_l[f] = *(const bf16x8*)&sBl[(brow + f * 16) * 32 + koff];
            if (PASSES == 3)
                a_l[f] = *(const bf16x8*)&sAl[(arow + f * 16) * 32 + koff];
        }
        #pragma unroll
        for (int i = 0; i < 4; ++i)
            #pragma unroll
            for (int j = 0; j < 4; ++j) {
                acc[i][j] = __builtin_amdgcn_mfma_f32_16x16x32_bf16(a_h[i], b_l[j], acc[i][j], 0, 0, 0);
                if (PASSES == 3)
                    acc[i][j] = __builtin_amdgcn_mfma_f32_16x16x32_bf16(a_l[i], b_h[j], acc[i][j], 0, 0, 0);
                acc[i][j] = __builtin_amdgcn_mfma_f32_16x16x32_bf16(a_h[i], b_h[j], acc[i][j], 0, 0, 0);
            }
        __syncthreads();
    }

    const int crow = (lane >> 4) * 4;
    const int ccol = lane & 15;

    if (EPI == 1) {
        #pragma unroll
        for (int i = 0; i < 4; ++i) {
            #pragma unroll
            for (int j = 0; j < 4; ++j) {
                const int n = n0 + wc * 64 + j * 16 + ccol;
                const float bv = bias[n];
                #pragma unroll
                for (int r = 0; r < 4; ++r) {
                    const int m = m0 + wr * 64 + i * 16 + crow + r;
                    outp[(size_t)m * CH + n] = acc[i][j][r] + bv;
                }
            }
        }
    } else {
        const int nblk = n0 + wc * 64;
        const int sec = nblk >> 10;           // 0=q 1=k 2=v
        const int h = (nblk & 1023) >> 6;
        float bv[4];
        #pragma unroll
        for (int j = 0; j < 4; ++j) bv[j] = bias[nblk + j * 16 + ccol];

        if (sec < 2) {
            const float* gp = (sec == 0) ? qg : kg;
            const float* bp = (sec == 0) ? qb_ : kb_;
            float g4[4], b4[4];
            #pragma unroll
            for (int j = 0; j < 4; ++j) { g4[j] = gp[j*16+ccol]; b4[j] = bp[j*16+ccol]; }
            const float scale = (sec == 0) ? 0.125f : 1.0f;
            _Float16* dst = (sec == 0) ? qf : kf;
            #pragma unroll
            for (int i = 0; i < 4; ++i) {
                #pragma unroll
                for (int r = 0; r < 4; ++r) {
                    const int m = m0 + wr * 64 + i * 16 + crow + r;
                    const int b_ = m >> 10, nn = m & 1023;
                    float vals[4], s = 0.f, q2 = 0.f;
                    #pragma unroll
                    for (int j = 0; j < 4; ++j) {
                        vals[j] = acc[i][j][r] + bv[j];
                        s += vals[j]; q2 += vals[j] * vals[j];
                    }
                    #pragma unroll
                    for (int o = 1; o < 16; o <<= 1) {
                        s  += __shfl_xor(s, o, 64);
                        q2 += __shfl_xor(q2, o, 64);
                    }
                    const float mean = s * 0.015625f;
                    const float var = q2 * 0.015625f - mean * mean;
                    const float rstd = rsqrtf(var + 1e-5f);
                    #pragma unroll
                    for (int j = 0; j < 4; ++j) {
                        const float y = ((vals[j] - mean) * rstd * g4[j] + b4[j]) * scale;
                        dst[((size_t)(b_ * NH + h) * SQ + nn) * HD + j * 16 + ccol] = (_Float16)y;
                    }
                }
            }
        } else {
            #pragma unroll
            for (int i = 0; i < 4; ++i) {
                const int m0r = m0 + wr * 64 + i * 16 + crow;
                const int b_ = m0r >> 10, nn0 = m0r & 1023;
                #pragma unroll
                for (int j = 0; j < 4; ++j) {
                    f16x4 tmp;
                    #pragma unroll
                    for (int r = 0; r < 4; ++r) tmp[r] = (_Float16)(acc[i][j][r] + bv[j]);
                    *(f16x4*)&vTf[((size_t)(b_ * NH + h) * HD + j * 16 + ccol) * SQ + nn0] = tmp;
                }
            }
        }
    }
}

// ---------- fused QK^T + softmax(no-max: |logit|<=8 rigorous) + weights + PV ----------
// In-block k-split: 4 waves = 2 q-groups x 2 k-halves; 64 q-rows per block,
// 1024 blocks -> 4 waves/SIMD (2x R10 occupancy). Phase-1 lsum exchanged via
// LDS; phase-2 W writes disjoint by k-half; PV partials reduced in LDS.
__global__ __launch_bounds__(256) void k_attn(
    const _Float16* __restrict__ q, const _Float16* __restrict__ k,
    const _Float16* __restrict__ vT, float* __restrict__ W,
    float* __restrict__ op)
{
    __shared__ _Float16 Pl[4][32][40];     // per-wave P staging
    __shared__ float Ored[2][32][68];      // PV partial exchange (padded)
    __shared__ float Ls[4][2][16];         // lsum partial exchange
    const int L = blockIdx.x;              // 1024 blocks
    const int bh   = (L & 7) * 8 + (L >> 7);
    const int xblk = (L >> 3) & 15;
    const int wid = threadIdx.x >> 6, lane = threadIdx.x & 63;
    const int qg2 = wid >> 1, kh2 = wid & 1;
    const int row0 = xblk * 64 + qg2 * 32;    // this wave's 32 q-rows
    const int lr = lane & 15, lg = lane >> 4;

    const _Float16* qh = q  + (size_t)bh * SQ * HD;
    const _Float16* kh = k  + (size_t)bh * SQ * HD;
    const _Float16* vh = vT + (size_t)bh * HD * SQ;

    f16x8 qb[2][2];
    #pragma unroll
    for (int qf = 0; qf < 2; ++qf)
        #pragma unroll
        for (int c = 0; c < 2; ++c)
            qb[qf][c] = *(const f16x8*)&qh[(size_t)(row0 + qf * 16 + lr) * HD + c * 32 + lg * 8];

    // ---- phase 1: partial row sums of exp(s) over this wave's k-half ----
    float lp0 = 0.f, lp1 = 0.f;
    const int kt0 = kh2 * 32;
    #pragma unroll 4
    for (int kt = kt0; kt < kt0 + 32; ++kt) {
        const f16x8 ka0 = *(const f16x8*)&kh[(size_t)(kt * 16 + lr) * HD + lg * 8];
        const f16x8 ka1 = *(const f16x8*)&kh[(size_t)(kt * 16 + lr) * HD + 32 + lg * 8];
        f32x4 s0 = (f32x4){0.f, 0.f, 0.f, 0.f};
        f32x4 s1 = (f32x4){0.f, 0.f, 0.f, 0.f};
        s0 = __builtin_amdgcn_mfma_f32_16x16x32_f16(ka0, qb[0][0], s0, 0, 0, 0);
        s0 = __builtin_amdgcn_mfma_f32_16x16x32_f16(ka1, qb[0][1], s0, 0, 0, 0);
        s1 = __builtin_amdgcn_mfma_f32_16x16x32_f16(ka0, qb[1][0], s1, 0, 0, 0);
        s1 = __builtin_amdgcn_mfma_f32_16x16x32_f16(ka1, qb[1][1], s1, 0, 0, 0);
        #pragma unroll
        for (int r = 0; r < 4; ++r) { lp0 += __expf(s0[r]); lp1 += __expf(s1[r]); }
    }
    lp0 += __shfl_xor(lp0, 16, 64); lp0 += __shfl_xor(lp0, 32, 64);
    lp1 += __shfl_xor(lp1, 16, 64); lp1 += __shfl_xor(lp1, 32, 64);
    if (lane < 16) { Ls[wid][0][lane] = lp0; Ls[wid][1][lane] = lp1; }
    __syncthreads();
    lp0 += Ls[wid ^ 1][0][lr];
    lp1 += Ls[wid ^ 1][1][lr];
    const float invl0 = 1.0f / lp0;      // q = row0 + lr
    const float invl1 = 1.0f / lp1;      // q = row0 + 16 + lr

    // ---- phase 2: recompute s over k-half, write W, accumulate PV partial ----
    float* Wr = W + (size_t)bh * SQ * SQ;
    f32x4 opv[4][2];
    #pragma unroll
    for (int dt = 0; dt < 4; ++dt)
        #pragma unroll
        for (int qf = 0; qf < 2; ++qf)
            opv[dt][qf] = (f32x4){0.f, 0.f, 0.f, 0.f};

    const int jc0 = kh2 * 16;
    for (int jc = jc0; jc < jc0 + 16; ++jc) {
        // V loads first — independent of P, free to fly early
        f16x8 vb[4];
        #pragma unroll
        for (int dt = 0; dt < 4; ++dt)
            vb[dt] = *(const f16x8*)&vh[(size_t)(dt * 16 + lr) * SQ + jc * 32 + lg * 8];

        #pragma unroll
        for (int t = 0; t < 2; ++t) {
            const int kt = jc * 2 + t;
            const f16x8 ka0 = *(const f16x8*)&kh[(size_t)(kt * 16 + lr) * HD + lg * 8];
            const f16x8 ka1 = *(const f16x8*)&kh[(size_t)(kt * 16 + lr) * HD + 32 + lg * 8];
            f32x4 s0 = (f32x4){0.f, 0.f, 0.f, 0.f};
            f32x4 s1 = (f32x4){0.f, 0.f, 0.f, 0.f};
            s0 = __builtin_amdgcn_mfma_f32_16x16x32_f16(ka0, qb[0][0], s0, 0, 0, 0);
            s0 = __builtin_amdgcn_mfma_f32_16x16x32_f16(ka1, qb[0][1], s0, 0, 0, 0);
            s1 = __builtin_amdgcn_mfma_f32_16x16x32_f16(ka0, qb[1][0], s1, 0, 0, 0);
            s1 = __builtin_amdgcn_mfma_f32_16x16x32_f16(ka1, qb[1][1], s1, 0, 0, 0);
            f32x4 wv0, wv1;
            f16x4 pv0, pv1;
            #pragma unroll
            for (int r = 0; r < 4; ++r) {
                wv0[r] = __expf(s0[r]) * invl0;  pv0[r] = (_Float16)wv0[r];
                wv1[r] = __expf(s1[r]) * invl1;  pv1[r] = (_Float16)wv1[r];
            }
            *(f32x4*)&Wr[(size_t)(row0 + lr) * SQ + kt * 16 + lg * 4]      = wv0;
            *(f32x4*)&Wr[(size_t)(row0 + 16 + lr) * SQ + kt * 16 + lg * 4] = wv1;
            *(f16x4*)&Pl[wid][lr][t * 16 + lg * 4]      = pv0;
            *(f16x4*)&Pl[wid][16 + lr][t * 16 + lg * 4] = pv1;
        }
        const f16x8 pa0 = *(const f16x8*)&Pl[wid][lr][lg * 8];
        const f16x8 pa1 = *(const f16x8*)&Pl[wid][16 + lr][lg * 8];
        #pragma unroll
        for (int dt = 0; dt < 4; ++dt) {
            opv[dt][0] = __builtin_amdgcn_mfma_f32_16x16x32_f16(pa0, vb[dt], opv[dt][0], 0, 0, 0);
            opv[dt][1] = __builtin_amdgcn_mfma_f32_16x16x32_f16(pa1, vb[dt], opv[dt][1], 0, 0, 0);
        }
    }

    // ---- reduce PV partials across k-half wave pairs ----
    if (kh2 == 1) {
        #pragma unroll
        for (int dt = 0; dt < 4; ++dt)
            #pragma unroll
            for (int qf = 0; qf < 2; ++qf)
                #pragma unroll
                for (int r = 0; r < 4; ++r)
                    Ored[qg2][qf * 16 + lg * 4 + r][dt * 16 + lr] = opv[dt][qf][r];
    }
    __syncthreads();
    if (kh2 == 0) {
        const int b_ = bh >> 4, h = bh & 15;
        #pragma unroll
        for (int dt = 0; dt < 4; ++dt)
            #pragma unroll
            for (int qf = 0; qf < 2; ++qf)
                #pragma unroll
                for (int r = 0; r < 4; ++r) {
                    const float val = opv[dt][qf][r]
                        + Ored[qg2][qf * 16 + lg * 4 + r][dt * 16 + lr];
                    const int row = row0 + qf * 16 + lg * 4 + r;
                    op[((size_t)(b_ * SQ + row)) * CH + h * HD + dt * 16 + lr] = val;
                }
    }
}

extern "C" void kernel_launch(void* const* d_in, const int* in_sizes, int n_in,
                              void* d_out, int out_size, void* d_ws, size_t ws_size,
                              hipStream_t stream)
{
    const float* x    = (const float*)d_in[0];
    const float* Wqkv = (const float*)d_in[1];
    const float* bqkv = (const float*)d_in[2];
    const float* qg   = (const float*)d_in[3];
    const float* qb   = (const float*)d_in[4];
    const float* kg   = (const float*)d_in[5];
    const float* kb   = (const float*)d_in[6];
    const float* Wp   = (const float*)d_in[7];
    const float* bp   = (const float*)d_in[8];

    float* out     = (float*)d_out;                       // [B,N,C]
    float* weights = out + (size_t)NB * SQ * CH;          // [B,H,N,N]

    // ws layout (MB): xh 0-8, (8-16 free), wqh 16-22, wql 22-28, wph 28-30,
    //                 wpl 30-32, qf 32-40, kf 40-48, vT 48-56, oph 56-64,
    //                 opl 64-72.  op (f32 16MB) aliases 0-16 after QKV GEMM.
    char* w = (char*)d_ws;
    __bf16*   xh  = (__bf16*)w;
    __bf16*   wqh = (__bf16*)(w + (((size_t)16) << 20));
    __bf16*   wql = (__bf16*)(w + (((size_t)22) << 20));
    __bf16*   wph = (__bf16*)(w + (((size_t)28) << 20));
    __bf16*   wpl = (__bf16*)(w + (((size_t)30) << 20));
    _Float16* qf  = (_Float16*)(w + (((size_t)32) << 20));
    _Float16* kf  = (_Float16*)(w + (((size_t)40) << 20));
    _Float16* vTf = (_Float16*)(w + (((size_t)48) << 20));
    __bf16*   oph = (__bf16*)(w + (((size_t)56) << 20));
    __bf16*   opl = (__bf16*)(w + (((size_t)64) << 20));
    float*    op  = (float*)w;                            // alias xh (x dead)

    // 0) splits: x hi-only (2-pass QKV), weights full hi/lo
    k_split_hi<<<(NB*SQ*CH/4 + 255)/256, 256, 0, stream>>>(x, xh, NB*SQ*CH/4);
    k_split<<<(3*CH*CH/4 + 255)/256, 256, 0, stream>>>(Wqkv, wqh, wql, 3*CH*CH/4);
    k_split<<<(CH*CH/4 + 255)/256, 256, 0, stream>>>(Wp, wph, wpl, CH*CH/4);

    // 1) qkv GEMM (2-pass) + fused bias+LN epilogue -> q,k fp16 (LN'd), vT fp16
    k_mfma_gemm<0, 2><<<dim3(24, 32), 256, 0, stream>>>(
        xh, nullptr, wqh, wql, bqkv, nullptr, qf, kf, vTf, qg, qb, kg, kb);

    // 2) fused attention (in-block k-split, 1024 blocks)
    k_attn<<<dim3(1024), 256, 0, stream>>>(qf, kf, vTf, weights, op);

    // 2b) split attention output to bf16 hi/lo for proj
    k_split<<<dim3(NB*SQ*CH/4/256), 256, 0, stream>>>(op, oph, opl, NB*SQ*CH/4);

    // 3) proj GEMM (3-pass: keep v->out path accurate)
    k_mfma_gemm<1, 3><<<dim3(8, 32), 256, 0, stream>>>(
        oph, opl, wph, wpl, bp, out, nullptr, nullptr, nullptr,
        nullptr, nullptr, nullptr, nullptr);
}

// Round 14
// 267.225 us; speedup vs baseline: 1.0051x; 1.0051x over previous
//
#include <hip/hip_runtime.h>
#include <math.h>

#define NH 16          // heads
#define HD 64          // head dim
#define NB 4           // batch
#define SQ 1024        // seq len
#define CH 1024        // channels

typedef __bf16   bf16x8 __attribute__((ext_vector_type(8)));
typedef __bf16   bf16x4 __attribute__((ext_vector_type(4)));
typedef _Float16 f16x8  __attribute__((ext_vector_type(8)));
typedef _Float16 f16x4  __attribute__((ext_vector_type(4)));
typedef float    f32x4  __attribute__((ext_vector_type(4)));

typedef const __attribute__((address_space(1))) void gvoid_t;
typedef __attribute__((address_space(3))) void lvoid_t;

// ---------- split fp32 -> bf16 hi/lo ----------
__global__ __launch_bounds__(256) void k_split(
    const float* __restrict__ in, __bf16* __restrict__ hi,
    __bf16* __restrict__ lo, int n4)
{
    const int idx = blockIdx.x * 256 + threadIdx.x;
    if (idx >= n4) return;
    const float4 v = ((const float4*)in)[idx];
    bf16x4 h, l;
    h[0] = (__bf16)v.x; l[0] = (__bf16)(v.x - (float)h[0]);
    h[1] = (__bf16)v.y; l[1] = (__bf16)(v.y - (float)h[1]);
    h[2] = (__bf16)v.z; l[2] = (__bf16)(v.z - (float)h[2]);
    h[3] = (__bf16)v.w; l[3] = (__bf16)(v.w - (float)h[3]);
    ((bf16x4*)hi)[idx] = h;
    ((bf16x4*)lo)[idx] = l;
}

// ---------- hi-only split (for x: 2-pass QKV GEMM needs no A_lo) ----------
__global__ __launch_bounds__(256) void k_split_hi(
    const float* __restrict__ in, __bf16* __restrict__ hi, int n4)
{
    const int idx = blockIdx.x * 256 + threadIdx.x;
    if (idx >= n4) return;
    const float4 v = ((const float4*)in)[idx];
    bf16x4 h;
    h[0] = (__bf16)v.x; h[1] = (__bf16)v.y;
    h[2] = (__bf16)v.z; h[3] = (__bf16)v.w;
    ((bf16x4*)hi)[idx] = h;
}

// ---------- split-bf16 MFMA GEMM: C = A @ B^T (+bias) ----------
// PASSES==3: acc += Ah*Bl + Al*Bh + Ah*Bh   (full split)
// PASSES==2: acc += Ah*Bl + Ah*Bh           (drop Al term; Al not staged)
template<int EPI, int PASSES>
__global__ __launch_bounds__(256) void k_mfma_gemm(
    const __bf16* __restrict__ Ah, const __bf16* __restrict__ Al,
    const __bf16* __restrict__ Bh, const __bf16* __restrict__ Bl,
    const float* __restrict__ bias, float* __restrict__ outp,
    _Float16* __restrict__ qf, _Float16* __restrict__ kf, _Float16* __restrict__ vTf,
    const float* __restrict__ qg, const float* __restrict__ qb_,
    const float* __restrict__ kg, const float* __restrict__ kb_)
{
    __shared__ __align__(16) __bf16 sAh[128 * 32];
    __shared__ __align__(16) __bf16 sAl[(PASSES == 3) ? 128 * 32 : 8];
    __shared__ __align__(16) __bf16 sBh[128 * 32];
    __shared__ __align__(16) __bf16 sBl[128 * 32];

    const int tid = threadIdx.x;
    const int wid = tid >> 6, lane = tid & 63;
    const int wr = wid >> 1, wc = wid & 1;
    const int m0 = blockIdx.y * 128, n0 = blockIdx.x * 128;

    f32x4 acc[4][4];
    #pragma unroll
    for (int i = 0; i < 4; ++i)
        #pragma unroll
        for (int j = 0; j < 4; ++j)
            acc[i][j] = (f32x4){0.f, 0.f, 0.f, 0.f};

    // staging assignment
    const __bf16* gsrc;
    __bf16* sdst;
    int nloads, ibase, gbase;
    if (PASSES == 3) {
        gsrc = (wid == 0) ? Ah : (wid == 1) ? Al : (wid == 2) ? Bh : Bl;
        sdst = (wid == 0) ? sAh : (wid == 1) ? sAl : (wid == 2) ? sBh : sBl;
        gbase = (wid < 2) ? m0 : n0;
        nloads = 8; ibase = 0;
    } else {
        gsrc = (wid == 1) ? Bh : (wid == 2) ? Bl : Ah;
        sdst = (wid == 1) ? sBh : (wid == 2) ? sBl : sAh;
        gbase = (wid == 1 || wid == 2) ? n0 : m0;
        nloads = (wid == 1 || wid == 2) ? 8 : 4;
        ibase = (wid == 3) ? 4 : 0;
    }
    const int grow = gbase + (lane >> 2);
    const int gcol = (lane & 3) * 8;

    const int arow = wr * 64 + (lane & 15);
    const int brow = wc * 64 + (lane & 15);
    const int koff = (lane >> 4) * 8;

    for (int k0 = 0; k0 < CH; k0 += 32) {
        for (int i = 0; i < nloads; ++i) {
            const __bf16* g = gsrc + (size_t)(grow + (ibase + i) * 16) * CH + k0 + gcol;
            __builtin_amdgcn_global_load_lds((gvoid_t*)g,
                                             (lvoid_t*)(sdst + (ibase + i) * 512),
                                             16, 0, 0);
        }
        __syncthreads();

        bf16x8 a_h[4], b_h[4], b_l[4];
        bf16x8 a_l[4];
        #pragma unroll
        for (int f = 0; f < 4; ++f) {
            a_h[f] = *(const bf16x8*)&sAh[(arow + f * 16) * 32 + koff];
            b_h[f] = *(const bf16x8*)&sBh[(brow + f * 16) * 32 + koff];
            b_l[f] = *(const bf16x8*)&sBl[(brow + f * 16) * 32 + koff];
            if (PASSES == 3)
                a_l[f] = *(const bf16x8*)&sAl[(arow + f * 16) * 32 + koff];
        }
        #pragma unroll
        for (int i = 0; i < 4; ++i)
            #pragma unroll
            for (int j = 0; j < 4; ++j) {
                acc[i][j] = __builtin_amdgcn_mfma_f32_16x16x32_bf16(a_h[i], b_l[j], acc[i][j], 0, 0, 0);
                if (PASSES == 3)
                    acc[i][j] = __builtin_amdgcn_mfma_f32_16x16x32_bf16(a_l[i], b_h[j], acc[i][j], 0, 0, 0);
                acc[i][j] = __builtin_amdgcn_mfma_f32_16x16x32_bf16(a_h[i], b_h[j], acc[i][j], 0, 0, 0);
            }
        __syncthreads();
    }

    const int crow = (lane >> 4) * 4;
    const int ccol = lane & 15;

    if (EPI == 1) {
        #pragma unroll
        for (int i = 0; i < 4; ++i) {
            #pragma unroll
            for (int j = 0; j < 4; ++j) {
                const int n = n0 + wc * 64 + j * 16 + ccol;
                const float bv = bias[n];
                #pragma unroll
                for (int r = 0; r < 4; ++r) {
                    const int m = m0 + wr * 64 + i * 16 + crow + r;
                    outp[(size_t)m * CH + n] = acc[i][j][r] + bv;
                }
            }
        }
    } else {
        const int nblk = n0 + wc * 64;
        const int sec = nblk >> 10;           // 0=q 1=k 2=v
        const int h = (nblk & 1023) >> 6;
        float bv[4];
        #pragma unroll
        for (int j = 0; j < 4; ++j) bv[j] = bias[nblk + j * 16 + ccol];

        if (sec < 2) {
            const float* gp = (sec == 0) ? qg : kg;
            const float* bp = (sec == 0) ? qb_ : kb_;
            float g4[4], b4[4];
            #pragma unroll
            for (int j = 0; j < 4; ++j) { g4[j] = gp[j*16+ccol]; b4[j] = bp[j*16+ccol]; }
            const float scale = (sec == 0) ? 0.125f : 1.0f;
            _Float16* dst = (sec == 0) ? qf : kf;
            #pragma unroll
            for (int i = 0; i < 4; ++i) {
                #pragma unroll
                for (int r = 0; r < 4; ++r) {
                    const int m = m0 + wr * 64 + i * 16 + crow + r;
                    const int b_ = m >> 10, nn = m & 1023;
                    float vals[4], s = 0.f, q2 = 0.f;
                    #pragma unroll
                    for (int j = 0; j < 4; ++j) {
                        vals[j] = acc[i][j][r] + bv[j];
                        s += vals[j]; q2 += vals[j] * vals[j];
                    }
                    #pragma unroll
                    for (int o = 1; o < 16; o <<= 1) {
                        s  += __shfl_xor(s, o, 64);
                        q2 += __shfl_xor(q2, o, 64);
                    }
                    const float mean = s * 0.015625f;
                    const float var = q2 * 0.015625f - mean * mean;
                    const float rstd = rsqrtf(var + 1e-5f);
                    #pragma unroll
                    for (int j = 0; j < 4; ++j) {
                        const float y = ((vals[j] - mean) * rstd * g4[j] + b4[j]) * scale;
                        dst[((size_t)(b_ * NH + h) * SQ + nn) * HD + j * 16 + ccol] = (_Float16)y;
                    }
                }
            }
        } else {
            #pragma unroll
            for (int i = 0; i < 4; ++i) {
                const int m0r = m0 + wr * 64 + i * 16 + crow;
                const int b_ = m0r >> 10, nn0 = m0r & 1023;
                #pragma unroll
                for (int j = 0; j < 4; ++j) {
                    f16x4 tmp;
                    #pragma unroll
                    for (int r = 0; r < 4; ++r) tmp[r] = (_Float16)(acc[i][j][r] + bv[j]);
                    *(f16x4*)&vTf[((size_t)(b_ * NH + h) * HD + j * 16 + ccol) * SQ + nn0] = tmp;
                }
            }
        }
    }
}

// ---------- fused QK^T + softmax(no-max: |logit|<=8 rigorous) + weights + PV ----------
// R12 structure (512 blocks, 32 q-rows/wave, swapped QK^T, XCD clustering) with
// LDS-staged W write-back: P tiles accumulate per-wave in LDS over 256-col
// chunks, then each row is written as 1KB-CONTIGUOUS f32x4 stores (16x better
// DRAM page locality than the 4KB-strided column sweep). W values are the f16
// P values (adds <=5e-4 abs; identical to what PV uses).
__global__ __launch_bounds__(256) void k_attn(
    const _Float16* __restrict__ q, const _Float16* __restrict__ k,
    const _Float16* __restrict__ vT, float* __restrict__ W,
    float* __restrict__ op)
{
    __shared__ _Float16 Pw[4][32][262];  // per-wave private; stride 262 breaks conflicts
    const int L = blockIdx.x;            // 512 blocks
    const int bh   = (L & 7) * 8 + (L >> 6);
    const int xblk = (L >> 3) & 7;
    const int wid = threadIdx.x >> 6, lane = threadIdx.x & 63;
    const int row0 = xblk * 128 + wid * 32;   // this wave's 32 q-rows
    const int lr = lane & 15, lg = lane >> 4;

    const _Float16* qh = q  + (size_t)bh * SQ * HD;
    const _Float16* kh = k  + (size_t)bh * SQ * HD;
    const _Float16* vh = vT + (size_t)bh * HD * SQ;

    f16x8 qb[2][2];
    #pragma unroll
    for (int qf = 0; qf < 2; ++qf)
        #pragma unroll
        for (int c = 0; c < 2; ++c)
            qb[qf][c] = *(const f16x8*)&qh[(size_t)(row0 + qf * 16 + lr) * HD + c * 32 + lg * 8];

    // ---- phase 1: per-q row sums of exp(s) ----
    float lp0 = 0.f, lp1 = 0.f;
    #pragma unroll 4
    for (int kt = 0; kt < 64; ++kt) {
        const f16x8 ka0 = *(const f16x8*)&kh[(size_t)(kt * 16 + lr) * HD + lg * 8];
        const f16x8 ka1 = *(const f16x8*)&kh[(size_t)(kt * 16 + lr) * HD + 32 + lg * 8];
        f32x4 s0 = (f32x4){0.f, 0.f, 0.f, 0.f};
        f32x4 s1 = (f32x4){0.f, 0.f, 0.f, 0.f};
        s0 = __builtin_amdgcn_mfma_f32_16x16x32_f16(ka0, qb[0][0], s0, 0, 0, 0);
        s0 = __builtin_amdgcn_mfma_f32_16x16x32_f16(ka1, qb[0][1], s0, 0, 0, 0);
        s1 = __builtin_amdgcn_mfma_f32_16x16x32_f16(ka0, qb[1][0], s1, 0, 0, 0);
        s1 = __builtin_amdgcn_mfma_f32_16x16x32_f16(ka1, qb[1][1], s1, 0, 0, 0);
        #pragma unroll
        for (int r = 0; r < 4; ++r) { lp0 += __expf(s0[r]); lp1 += __expf(s1[r]); }
    }
    lp0 += __shfl_xor(lp0, 16, 64); lp0 += __shfl_xor(lp0, 32, 64);
    lp1 += __shfl_xor(lp1, 16, 64); lp1 += __shfl_xor(lp1, 32, 64);
    const float invl0 = 1.0f / lp0;      // q = row0 + lr
    const float invl1 = 1.0f / lp1;      // q = row0 + 16 + lr

    // ---- phase 2: 4 chunks of 256 k-cols ----
    float* Wr = W + (size_t)bh * SQ * SQ;
    f32x4 opv[4][2];
    #pragma unroll
    for (int dt = 0; dt < 4; ++dt)
        #pragma unroll
        for (int qf = 0; qf < 2; ++qf)
            opv[dt][qf] = (f32x4){0.f, 0.f, 0.f, 0.f};

    for (int ch = 0; ch < 4; ++ch) {
        for (int jcl = 0; jcl < 8; ++jcl) {      // 8 x 32 cols per chunk
            const int jc = ch * 8 + jcl;
            // V loads first — independent of P, free to fly early
            f16x8 vb[4];
            #pragma unroll
            for (int dt = 0; dt < 4; ++dt)
                vb[dt] = *(const f16x8*)&vh[(size_t)(dt * 16 + lr) * SQ + jc * 32 + lg * 8];

            #pragma unroll
            for (int t = 0; t < 2; ++t) {
                const int kt = jc * 2 + t;
                const f16x8 ka0 = *(const f16x8*)&kh[(size_t)(kt * 16 + lr) * HD + lg * 8];
                const f16x8 ka1 = *(const f16x8*)&kh[(size_t)(kt * 16 + lr) * HD + 32 + lg * 8];
                f32x4 s0 = (f32x4){0.f, 0.f, 0.f, 0.f};
                f32x4 s1 = (f32x4){0.f, 0.f, 0.f, 0.f};
                s0 = __builtin_amdgcn_mfma_f32_16x16x32_f16(ka0, qb[0][0], s0, 0, 0, 0);
                s0 = __builtin_amdgcn_mfma_f32_16x16x32_f16(ka1, qb[0][1], s0, 0, 0, 0);
                s1 = __builtin_amdgcn_mfma_f32_16x16x32_f16(ka0, qb[1][0], s1, 0, 0, 0);
                s1 = __builtin_amdgcn_mfma_f32_16x16x32_f16(ka1, qb[1][1], s1, 0, 0, 0);
                f16x4 pv0, pv1;
                #pragma unroll
                for (int r = 0; r < 4; ++r) {
                    pv0[r] = (_Float16)(__expf(s0[r]) * invl0);
                    pv1[r] = (_Float16)(__expf(s1[r]) * invl1);
                }
                *(f16x4*)&Pw[wid][lr][jcl * 32 + t * 16 + lg * 4]      = pv0;
                *(f16x4*)&Pw[wid][16 + lr][jcl * 32 + t * 16 + lg * 4] = pv1;
            }
            const f16x8 pa0 = *(const f16x8*)&Pw[wid][lr][jcl * 32 + lg * 8];
            const f16x8 pa1 = *(const f16x8*)&Pw[wid][16 + lr][jcl * 32 + lg * 8];
            #pragma unroll
            for (int dt = 0; dt < 4; ++dt) {
                opv[dt][0] = __builtin_amdgcn_mfma_f32_16x16x32_f16(pa0, vb[dt], opv[dt][0], 0, 0, 0);
                opv[dt][1] = __builtin_amdgcn_mfma_f32_16x16x32_f16(pa1, vb[dt], opv[dt][1], 0, 0, 0);
            }
        }
        // write-back: 32 rows x 1KB contiguous f32 stores (from f16 P)
        #pragma unroll 8
        for (int r = 0; r < 32; ++r) {
            const f16x4 pv = *(const f16x4*)&Pw[wid][r][lane * 4];
            f32x4 wv;
            #pragma unroll
            for (int j = 0; j < 4; ++j) wv[j] = (float)pv[j];
            *(f32x4*)&Wr[(size_t)(row0 + r) * SQ + ch * 256 + lane * 4] = wv;
        }
    }

    // epilogue: write attention output as f32 [B,N,C] (split pass makes hi/lo)
    const int b_ = bh >> 4, h = bh & 15;
    #pragma unroll
    for (int dt = 0; dt < 4; ++dt)
        #pragma unroll
        for (int qf = 0; qf < 2; ++qf)
            #pragma unroll
            for (int r = 0; r < 4; ++r) {
                const int row = row0 + qf * 16 + lg * 4 + r;
                op[((size_t)(b_ * SQ + row)) * CH + h * HD + dt * 16 + lr] = opv[dt][qf][r];
            }
}

extern "C" void kernel_launch(void* const* d_in, const int* in_sizes, int n_in,
                              void* d_out, int out_size, void* d_ws, size_t ws_size,
                              hipStream_t stream)
{
    const float* x    = (const float*)d_in[0];
    const float* Wqkv = (const float*)d_in[1];
    const float* bqkv = (const float*)d_in[2];
    const float* qg   = (const float*)d_in[3];
    const float* qb   = (const float*)d_in[4];
    const float* kg   = (const float*)d_in[5];
    const float* kb   = (const float*)d_in[6];
    const float* Wp   = (const float*)d_in[7];
    const float* bp   = (const float*)d_in[8];

    float* out     = (float*)d_out;                       // [B,N,C]
    float* weights = out + (size_t)NB * SQ * CH;          // [B,H,N,N]

    // ws layout (MB): xh 0-8, (8-16 free), wqh 16-22, wql 22-28, wph 28-30,
    //                 wpl 30-32, qf 32-40, kf 40-48, vT 48-56, oph 56-64,
    //                 opl 64-72.  op (f32 16MB) aliases 0-16 after QKV GEMM.
    char* w = (char*)d_ws;
    __bf16*   xh  = (__bf16*)w;
    __bf16*   wqh = (__bf16*)(w + (((size_t)16) << 20));
    __bf16*   wql = (__bf16*)(w + (((size_t)22) << 20));
    __bf16*   wph = (__bf16*)(w + (((size_t)28) << 20));
    __bf16*   wpl = (__bf16*)(w + (((size_t)30) << 20));
    _Float16* qf  = (_Float16*)(w + (((size_t)32) << 20));
    _Float16* kf  = (_Float16*)(w + (((size_t)40) << 20));
    _Float16* vTf = (_Float16*)(w + (((size_t)48) << 20));
    __bf16*   oph = (__bf16*)(w + (((size_t)56) << 20));
    __bf16*   opl = (__bf16*)(w + (((size_t)64) << 20));
    float*    op  = (float*)w;                            // alias xh (x dead)

    // 0) splits: x hi-only (2-pass QKV), weights full hi/lo
    k_split_hi<<<(NB*SQ*CH/4 + 255)/256, 256, 0, stream>>>(x, xh, NB*SQ*CH/4);
    k_split<<<(3*CH*CH/4 + 255)/256, 256, 0, stream>>>(Wqkv, wqh, wql, 3*CH*CH/4);
    k_split<<<(CH*CH/4 + 255)/256, 256, 0, stream>>>(Wp, wph, wpl, CH*CH/4);

    // 1) qkv GEMM (2-pass) + fused bias+LN epilogue -> q,k fp16 (LN'd), vT fp16
    k_mfma_gemm<0, 2><<<dim3(24, 32), 256, 0, stream>>>(
        xh, nullptr, wqh, wql, bqkv, nullptr, qf, kf, vTf, qg, qb, kg, kb);

    // 2) fused attention: QK^T + exact softmax + LDS-staged weights + PV
    k_attn<<<dim3(512), 256, 0, stream>>>(qf, kf, vTf, weights, op);

    // 2b) split attention output to bf16 hi/lo for proj
    k_split<<<dim3(NB*SQ*CH/4/256), 256, 0, stream>>>(op, oph, opl, NB*SQ*CH/4);

    // 3) proj GEMM (3-pass: keep v->out path accurate)
    k_mfma_gemm<1, 3><<<dim3(8, 32), 256, 0, stream>>>(
        oph, opl, wph, wpl, bp, out, nullptr, nullptr, nullptr,
        nullptr, nullptr, nullptr, nullptr);
}

// Round 15
// 246.907 us; speedup vs baseline: 1.0878x; 1.0823x over previous
//
#include <hip/hip_runtime.h>
#include <math.h>

#define NH 16          // heads
#define HD 64          // head dim
#define NB 4           // batch
#define SQ 1024        // seq len
#define CH 1024        // channels

typedef __bf16   bf16x8 __attribute__((ext_vector_type(8)));
typedef __bf16   bf16x4 __attribute__((ext_vector_type(4)));
typedef _Float16 f16x8  __attribute__((ext_vector_type(8)));
typedef _Float16 f16x4  __attribute__((ext_vector_type(4)));
typedef float    f32x4  __attribute__((ext_vector_type(4)));

typedef const __attribute__((address_space(1))) void gvoid_t;
typedef __attribute__((address_space(3))) void lvoid_t;

// ---------- one-pass input splitter: x (hi only), Wqkv (hi/lo), Wp (hi/lo) ----------
#define NQ_X   (NB * SQ * CH / 4)        // 1048576 float4s
#define NQ_WQ  (3 * CH * CH / 4)         // 786432
#define NQ_WP  (CH * CH / 4)             // 262144
__global__ __launch_bounds__(256) void k_split_all(
    const float* __restrict__ x, const float* __restrict__ wqkv,
    const float* __restrict__ wp,
    __bf16* __restrict__ xh,
    __bf16* __restrict__ wqh, __bf16* __restrict__ wql,
    __bf16* __restrict__ wph, __bf16* __restrict__ wpl)
{
    int i = blockIdx.x * 256 + threadIdx.x;
    if (i < NQ_X) {
        const float4 v = ((const float4*)x)[i];
        bf16x4 h;
        h[0] = (__bf16)v.x; h[1] = (__bf16)v.y;
        h[2] = (__bf16)v.z; h[3] = (__bf16)v.w;
        ((bf16x4*)xh)[i] = h;
        return;
    }
    i -= NQ_X;
    const float4 v = (i < NQ_WQ) ? ((const float4*)wqkv)[i]
                                 : ((const float4*)wp)[i - NQ_WQ];
    bf16x4 h, l;
    h[0] = (__bf16)v.x; l[0] = (__bf16)(v.x - (float)h[0]);
    h[1] = (__bf16)v.y; l[1] = (__bf16)(v.y - (float)h[1]);
    h[2] = (__bf16)v.z; l[2] = (__bf16)(v.z - (float)h[2]);
    h[3] = (__bf16)v.w; l[3] = (__bf16)(v.w - (float)h[3]);
    if (i < NQ_WQ) {
        ((bf16x4*)wqh)[i] = h;
        ((bf16x4*)wql)[i] = l;
    } else {
        ((bf16x4*)wph)[i - NQ_WQ] = h;
        ((bf16x4*)wpl)[i - NQ_WQ] = l;
    }
}

// ---------- split-bf16 MFMA GEMM: C = A @ B^T (+bias) ----------
// PASSES==3: acc += Ah*Bl + Al*Bh + Ah*Bh   (full split)
// PASSES==2: acc += Ah*Bl + Ah*Bh           (drop Al term; Al not staged)
template<int EPI, int PASSES>
__global__ __launch_bounds__(256) void k_mfma_gemm(
    const __bf16* __restrict__ Ah, const __bf16* __restrict__ Al,
    const __bf16* __restrict__ Bh, const __bf16* __restrict__ Bl,
    const float* __restrict__ bias, float* __restrict__ outp,
    _Float16* __restrict__ qf, _Float16* __restrict__ kf, _Float16* __restrict__ vTf,
    const float* __restrict__ qg, const float* __restrict__ qb_,
    const float* __restrict__ kg, const float* __restrict__ kb_)
{
    __shared__ __align__(16) __bf16 sAh[128 * 32];
    __shared__ __align__(16) __bf16 sAl[(PASSES == 3) ? 128 * 32 : 8];
    __shared__ __align__(16) __bf16 sBh[128 * 32];
    __shared__ __align__(16) __bf16 sBl[128 * 32];

    const int tid = threadIdx.x;
    const int wid = tid >> 6, lane = tid & 63;
    const int wr = wid >> 1, wc = wid & 1;
    const int m0 = blockIdx.y * 128, n0 = blockIdx.x * 128;

    f32x4 acc[4][4];
    #pragma unroll
    for (int i = 0; i < 4; ++i)
        #pragma unroll
        for (int j = 0; j < 4; ++j)
            acc[i][j] = (f32x4){0.f, 0.f, 0.f, 0.f};

    // staging assignment
    const __bf16* gsrc;
    __bf16* sdst;
    int nloads, ibase, gbase;
    if (PASSES == 3) {
        gsrc = (wid == 0) ? Ah : (wid == 1) ? Al : (wid == 2) ? Bh : Bl;
        sdst = (wid == 0) ? sAh : (wid == 1) ? sAl : (wid == 2) ? sBh : sBl;
        gbase = (wid < 2) ? m0 : n0;
        nloads = 8; ibase = 0;
    } else {
        gsrc = (wid == 1) ? Bh : (wid == 2) ? Bl : Ah;
        sdst = (wid == 1) ? sBh : (wid == 2) ? sBl : sAh;
        gbase = (wid == 1 || wid == 2) ? n0 : m0;
        nloads = (wid == 1 || wid == 2) ? 8 : 4;
        ibase = (wid == 3) ? 4 : 0;
    }
    const int grow = gbase + (lane >> 2);
    const int gcol = (lane & 3) * 8;

    const int arow = wr * 64 + (lane & 15);
    const int brow = wc * 64 + (lane & 15);
    const int koff = (lane >> 4) * 8;

    for (int k0 = 0; k0 < CH; k0 += 32) {
        for (int i = 0; i < nloads; ++i) {
            const __bf16* g = gsrc + (size_t)(grow + (ibase + i) * 16) * CH + k0 + gcol;
            __builtin_amdgcn_global_load_lds((gvoid_t*)g,
                                             (lvoid_t*)(sdst + (ibase + i) * 512),
                                             16, 0, 0);
        }
        __syncthreads();

        bf16x8 a_h[4], b_h[4], b_l[4];
        bf16x8 a_l[4];
        #pragma unroll
        for (int f = 0; f < 4; ++f) {
            a_h[f] = *(const bf16x8*)&sAh[(arow + f * 16) * 32 + koff];
            b_h[f] = *(const bf16x8*)&sBh[(brow + f * 16) * 32 + koff];
            b_l[f] = *(const bf16x8*)&sBl[(brow + f * 16) * 32 + koff];
            if (PASSES == 3)
                a_l[f] = *(const bf16x8*)&sAl[(arow + f * 16) * 32 + koff];
        }
        #pragma unroll
        for (int i = 0; i < 4; ++i)
            #pragma unroll
            for (int j = 0; j < 4; ++j) {
                acc[i][j] = __builtin_amdgcn_mfma_f32_16x16x32_bf16(a_h[i], b_l[j], acc[i][j], 0, 0, 0);
                if (PASSES == 3)
                    acc[i][j] = __builtin_amdgcn_mfma_f32_16x16x32_bf16(a_l[i], b_h[j], acc[i][j], 0, 0, 0);
                acc[i][j] = __builtin_amdgcn_mfma_f32_16x16x32_bf16(a_h[i], b_h[j], acc[i][j], 0, 0, 0);
            }
        __syncthreads();
    }

    const int crow = (lane >> 4) * 4;
    const int ccol = lane & 15;

    if (EPI == 1) {
        #pragma unroll
        for (int i = 0; i < 4; ++i) {
            #pragma unroll
            for (int j = 0; j < 4; ++j) {
                const int n = n0 + wc * 64 + j * 16 + ccol;
                const float bv = bias[n];
                #pragma unroll
                for (int r = 0; r < 4; ++r) {
                    const int m = m0 + wr * 64 + i * 16 + crow + r;
                    outp[(size_t)m * CH + n] = acc[i][j][r] + bv;
                }
            }
        }
    } else {
        const int nblk = n0 + wc * 64;
        const int sec = nblk >> 10;           // 0=q 1=k 2=v
        const int h = (nblk & 1023) >> 6;
        float bv[4];
        #pragma unroll
        for (int j = 0; j < 4; ++j) bv[j] = bias[nblk + j * 16 + ccol];

        if (sec < 2) {
            const float* gp = (sec == 0) ? qg : kg;
            const float* bp = (sec == 0) ? qb_ : kb_;
            float g4[4], b4[4];
            #pragma unroll
            for (int j = 0; j < 4; ++j) { g4[j] = gp[j*16+ccol]; b4[j] = bp[j*16+ccol]; }
            const float scale = (sec == 0) ? 0.125f : 1.0f;
            _Float16* dst = (sec == 0) ? qf : kf;
            #pragma unroll
            for (int i = 0; i < 4; ++i) {
                #pragma unroll
                for (int r = 0; r < 4; ++r) {
                    const int m = m0 + wr * 64 + i * 16 + crow + r;
                    const int b_ = m >> 10, nn = m & 1023;
                    float vals[4], s = 0.f, q2 = 0.f;
                    #pragma unroll
                    for (int j = 0; j < 4; ++j) {
                        vals[j] = acc[i][j][r] + bv[j];
                        s += vals[j]; q2 += vals[j] * vals[j];
                    }
                    #pragma unroll
                    for (int o = 1; o < 16; o <<= 1) {
                        s  += __shfl_xor(s, o, 64);
                        q2 += __shfl_xor(q2, o, 64);
                    }
                    const float mean = s * 0.015625f;
                    const float var = q2 * 0.015625f - mean * mean;
                    const float rstd = rsqrtf(var + 1e-5f);
                    #pragma unroll
                    for (int j = 0; j < 4; ++j) {
                        const float y = ((vals[j] - mean) * rstd * g4[j] + b4[j]) * scale;
                        dst[((size_t)(b_ * NH + h) * SQ + nn) * HD + j * 16 + ccol] = (_Float16)y;
                    }
                }
            }
        } else {
            #pragma unroll
            for (int i = 0; i < 4; ++i) {
                const int m0r = m0 + wr * 64 + i * 16 + crow;
                const int b_ = m0r >> 10, nn0 = m0r & 1023;
                #pragma unroll
                for (int j = 0; j < 4; ++j) {
                    f16x4 tmp;
                    #pragma unroll
                    for (int r = 0; r < 4; ++r) tmp[r] = (_Float16)(acc[i][j][r] + bv[j]);
                    *(f16x4*)&vTf[((size_t)(b_ * NH + h) * HD + j * 16 + ccol) * SQ + nn0] = tmp;
                }
            }
        }
    }
}

// ---------- fused QK^T + softmax(no-max: |logit|<=8 rigorous) + weights + PV ----------
// R12 core (512 blocks, 32 q-rows/wave, swapped QK^T, plain f32x4 W stores,
// XCD clustering, V loads before stores). Epilogue now emits bf16 hi/lo of
// the attention output directly (LDS transpose), removing the separate
// split pass and the 16MB f32 op write.
__global__ __launch_bounds__(256) void k_attn(
    const _Float16* __restrict__ q, const _Float16* __restrict__ k,
    const _Float16* __restrict__ vT, float* __restrict__ W,
    __bf16* __restrict__ oph, __bf16* __restrict__ opl)
{
    __shared__ _Float16 Pl[4][32][40];   // padded rows (80B): no 8-way conflicts
    __shared__ float Of[4][32][72];      // epilogue transpose (wave-private)
    const int L = blockIdx.x;            // 512 blocks
    const int bh   = (L & 7) * 8 + (L >> 6);
    const int xblk = (L >> 3) & 7;
    const int wid = threadIdx.x >> 6, lane = threadIdx.x & 63;
    const int row0 = xblk * 128 + wid * 32;   // this wave's 32 q-rows
    const int lr = lane & 15, lg = lane >> 4;

    const _Float16* qh = q  + (size_t)bh * SQ * HD;
    const _Float16* kh = k  + (size_t)bh * SQ * HD;
    const _Float16* vh = vT + (size_t)bh * HD * SQ;

    f16x8 qb[2][2];
    #pragma unroll
    for (int qf = 0; qf < 2; ++qf)
        #pragma unroll
        for (int c = 0; c < 2; ++c)
            qb[qf][c] = *(const f16x8*)&qh[(size_t)(row0 + qf * 16 + lr) * HD + c * 32 + lg * 8];

    // ---- phase 1: per-q row sums of exp(s) ----
    float lp0 = 0.f, lp1 = 0.f;
    #pragma unroll 4
    for (int kt = 0; kt < 64; ++kt) {
        const f16x8 ka0 = *(const f16x8*)&kh[(size_t)(kt * 16 + lr) * HD + lg * 8];
        const f16x8 ka1 = *(const f16x8*)&kh[(size_t)(kt * 16 + lr) * HD + 32 + lg * 8];
        f32x4 s0 = (f32x4){0.f, 0.f, 0.f, 0.f};
        f32x4 s1 = (f32x4){0.f, 0.f, 0.f, 0.f};
        s0 = __builtin_amdgcn_mfma_f32_16x16x32_f16(ka0, qb[0][0], s0, 0, 0, 0);
        s0 = __builtin_amdgcn_mfma_f32_16x16x32_f16(ka1, qb[0][1], s0, 0, 0, 0);
        s1 = __builtin_amdgcn_mfma_f32_16x16x32_f16(ka0, qb[1][0], s1, 0, 0, 0);
        s1 = __builtin_amdgcn_mfma_f32_16x16x32_f16(ka1, qb[1][1], s1, 0, 0, 0);
        #pragma unroll
        for (int r = 0; r < 4; ++r) { lp0 += __expf(s0[r]); lp1 += __expf(s1[r]); }
    }
    lp0 += __shfl_xor(lp0, 16, 64); lp0 += __shfl_xor(lp0, 32, 64);
    lp1 += __shfl_xor(lp1, 16, 64); lp1 += __shfl_xor(lp1, 32, 64);
    const float invl0 = 1.0f / lp0;      // q = row0 + lr
    const float invl1 = 1.0f / lp1;      // q = row0 + 16 + lr

    // ---- phase 2: recompute s, write weights (plain f32x4), PV ----
    float* Wr = W + (size_t)bh * SQ * SQ;
    f32x4 opv[4][2];
    #pragma unroll
    for (int dt = 0; dt < 4; ++dt)
        #pragma unroll
        for (int qf = 0; qf < 2; ++qf)
            opv[dt][qf] = (f32x4){0.f, 0.f, 0.f, 0.f};

    for (int jc = 0; jc < 32; ++jc) {          // 32-k chunks
        // V loads first — independent of P, free to fly early
        f16x8 vb[4];
        #pragma unroll
        for (int dt = 0; dt < 4; ++dt)
            vb[dt] = *(const f16x8*)&vh[(size_t)(dt * 16 + lr) * SQ + jc * 32 + lg * 8];

        #pragma unroll
        for (int t = 0; t < 2; ++t) {
            const int kt = jc * 2 + t;
            const f16x8 ka0 = *(const f16x8*)&kh[(size_t)(kt * 16 + lr) * HD + lg * 8];
            const f16x8 ka1 = *(const f16x8*)&kh[(size_t)(kt * 16 + lr) * HD + 32 + lg * 8];
            f32x4 s0 = (f32x4){0.f, 0.f, 0.f, 0.f};
            f32x4 s1 = (f32x4){0.f, 0.f, 0.f, 0.f};
            s0 = __builtin_amdgcn_mfma_f32_16x16x32_f16(ka0, qb[0][0], s0, 0, 0, 0);
            s0 = __builtin_amdgcn_mfma_f32_16x16x32_f16(ka1, qb[0][1], s0, 0, 0, 0);
            s1 = __builtin_amdgcn_mfma_f32_16x16x32_f16(ka0, qb[1][0], s1, 0, 0, 0);
            s1 = __builtin_amdgcn_mfma_f32_16x16x32_f16(ka1, qb[1][1], s1, 0, 0, 0);
            f32x4 wv0, wv1;
            f16x4 pv0, pv1;
            #pragma unroll
            for (int r = 0; r < 4; ++r) {
                wv0[r] = __expf(s0[r]) * invl0;  pv0[r] = (_Float16)wv0[r];
                wv1[r] = __expf(s1[r]) * invl1;  pv1[r] = (_Float16)wv1[r];
            }
            *(f32x4*)&Wr[(size_t)(row0 + lr) * SQ + kt * 16 + lg * 4]      = wv0;
            *(f32x4*)&Wr[(size_t)(row0 + 16 + lr) * SQ + kt * 16 + lg * 4] = wv1;
            *(f16x4*)&Pl[wid][lr][t * 16 + lg * 4]      = pv0;
            *(f16x4*)&Pl[wid][16 + lr][t * 16 + lg * 4] = pv1;
        }
        const f16x8 pa0 = *(const f16x8*)&Pl[wid][lr][lg * 8];
        const f16x8 pa1 = *(const f16x8*)&Pl[wid][16 + lr][lg * 8];
        #pragma unroll
        for (int dt = 0; dt < 4; ++dt) {
            opv[dt][0] = __builtin_amdgcn_mfma_f32_16x16x32_f16(pa0, vb[dt], opv[dt][0], 0, 0, 0);
            opv[dt][1] = __builtin_amdgcn_mfma_f32_16x16x32_f16(pa1, vb[dt], opv[dt][1], 0, 0, 0);
        }
    }

    // ---- epilogue: LDS transpose -> row-major bf16 hi/lo [B,N,C] ----
    #pragma unroll
    for (int dt = 0; dt < 4; ++dt)
        #pragma unroll
        for (int qf = 0; qf < 2; ++qf)
            #pragma unroll
            for (int r = 0; r < 4; ++r)
                Of[wid][qf * 16 + lg * 4 + r][dt * 16 + lr] = opv[dt][qf][r];
    // wave-private buffer: compiler inserts lgkmcnt waits; no barrier needed
    const int b_ = bh >> 4, h = bh & 15;
    #pragma unroll
    for (int p = 0; p < 4; ++p) {
        const int r = p * 8 + (lane >> 3);
        const int c = (lane & 7) * 8;
        bf16x8 hv, lv;
        #pragma unroll
        for (int j = 0; j < 8; ++j) {
            const float v = Of[wid][r][c + j];
            const __bf16 hh = (__bf16)v;
            hv[j] = hh;
            lv[j] = (__bf16)(v - (float)hh);
        }
        const size_t o = ((size_t)(b_ * SQ + row0 + r)) * CH + h * HD + c;
        *(bf16x8*)&oph[o] = hv;
        *(bf16x8*)&opl[o] = lv;
    }
}

extern "C" void kernel_launch(void* const* d_in, const int* in_sizes, int n_in,
                              void* d_out, int out_size, void* d_ws, size_t ws_size,
                              hipStream_t stream)
{
    const float* x    = (const float*)d_in[0];
    const float* Wqkv = (const float*)d_in[1];
    const float* bqkv = (const float*)d_in[2];
    const float* qg   = (const float*)d_in[3];
    const float* qb   = (const float*)d_in[4];
    const float* kg   = (const float*)d_in[5];
    const float* kb   = (const float*)d_in[6];
    const float* Wp   = (const float*)d_in[7];
    const float* bp   = (const float*)d_in[8];

    float* out     = (float*)d_out;                       // [B,N,C]
    float* weights = out + (size_t)NB * SQ * CH;          // [B,H,N,N]

    // ws layout (MB): xh 0-8, wqh 16-22, wql 22-28, wph 28-30, wpl 30-32,
    //                 qf 32-40, kf 40-48, vT 48-56, oph 56-64, opl 64-72
    char* w = (char*)d_ws;
    __bf16*   xh  = (__bf16*)w;
    __bf16*   wqh = (__bf16*)(w + (((size_t)16) << 20));
    __bf16*   wql = (__bf16*)(w + (((size_t)22) << 20));
    __bf16*   wph = (__bf16*)(w + (((size_t)28) << 20));
    __bf16*   wpl = (__bf16*)(w + (((size_t)30) << 20));
    _Float16* qf  = (_Float16*)(w + (((size_t)32) << 20));
    _Float16* kf  = (_Float16*)(w + (((size_t)40) << 20));
    _Float16* vTf = (_Float16*)(w + (((size_t)48) << 20));
    __bf16*   oph = (__bf16*)(w + (((size_t)56) << 20));
    __bf16*   opl = (__bf16*)(w + (((size_t)64) << 20));

    // 0) one-pass splits: x hi-only (2-pass QKV), Wqkv + Wp hi/lo
    k_split_all<<<dim3((NQ_X + NQ_WQ + NQ_WP) / 256), 256, 0, stream>>>(
        x, Wqkv, Wp, xh, wqh, wql, wph, wpl);

    // 1) qkv GEMM (2-pass) + fused bias+LN epilogue -> q,k fp16 (LN'd), vT fp16
    k_mfma_gemm<0, 2><<<dim3(24, 32), 256, 0, stream>>>(
        xh, nullptr, wqh, wql, bqkv, nullptr, qf, kf, vTf, qg, qb, kg, kb);

    // 2) fused attention: QK^T + exact softmax + weights + PV -> bf16 hi/lo
    k_attn<<<dim3(512), 256, 0, stream>>>(qf, kf, vTf, weights, oph, opl);

    // 3) proj GEMM (3-pass: keep v->out path accurate)
    k_mfma_gemm<1, 3><<<dim3(8, 32), 256, 0, stream>>>(
        oph, opl, wph, wpl, bp, out, nullptr, nullptr, nullptr,
        nullptr, nullptr, nullptr, nullptr);
}

// Round 16
// 195.945 us; speedup vs baseline: 1.3708x; 1.2601x over previous
//
#include <hip/hip_runtime.h>
#include <math.h>

#define NH 16          // heads
#define HD 64          // head dim
#define NB 4           // batch
#define SQ 1024        // seq len
#define CH 1024        // channels

typedef _Float16 f16x8  __attribute__((ext_vector_type(8)));
typedef _Float16 f16x4  __attribute__((ext_vector_type(4)));
typedef float    f32x4  __attribute__((ext_vector_type(4)));

typedef const __attribute__((address_space(1))) void gvoid_t;
typedef __attribute__((address_space(3))) void lvoid_t;

// ---------- one-pass fp32 -> fp16 converter: x, Wqkv, Wp ----------
#define NQ_X   (NB * SQ * CH / 4)        // 1048576 float4s
#define NQ_WQ  (3 * CH * CH / 4)         // 786432
#define NQ_WP  (CH * CH / 4)             // 262144
__global__ __launch_bounds__(256) void k_split_all(
    const float* __restrict__ x, const float* __restrict__ wqkv,
    const float* __restrict__ wp,
    _Float16* __restrict__ xf, _Float16* __restrict__ wqf,
    _Float16* __restrict__ wpf)
{
    int i = blockIdx.x * 256 + threadIdx.x;
    const float4 v = (i < NQ_X) ? ((const float4*)x)[i]
                   : (i < NQ_X + NQ_WQ) ? ((const float4*)wqkv)[i - NQ_X]
                   : ((const float4*)wp)[i - NQ_X - NQ_WQ];
    f16x4 h;
    h[0] = (_Float16)v.x; h[1] = (_Float16)v.y;
    h[2] = (_Float16)v.z; h[3] = (_Float16)v.w;
    if (i < NQ_X)             ((f16x4*)xf)[i] = h;
    else if (i < NQ_X + NQ_WQ)((f16x4*)wqf)[i - NQ_X] = h;
    else                      ((f16x4*)wpf)[i - NQ_X - NQ_WQ] = h;
}

// ---------- single-pass fp16 MFMA GEMM: C = A @ B^T (+bias) ----------
// fp16 (11-bit mantissa) beats the old 2-pass bf16 split: per-operand
// round-off 2^-11 with random-sign accumulation over K=1024 ~ 3e-4 abs.
// EPI 0: fused LN epilogue -> q,k fp16 (LN'd, q scaled), vT fp16 [B,H,D,N]
// EPI 1: plain fp32 out [M][1024]
template<int EPI>
__global__ __launch_bounds__(256) void k_mfma_gemm(
    const _Float16* __restrict__ A, const _Float16* __restrict__ B,
    const float* __restrict__ bias, float* __restrict__ outp,
    _Float16* __restrict__ qf, _Float16* __restrict__ kf, _Float16* __restrict__ vTf,
    const float* __restrict__ qg, const float* __restrict__ qb_,
    const float* __restrict__ kg, const float* __restrict__ kb_)
{
    __shared__ __align__(16) _Float16 sA[128 * 32];
    __shared__ __align__(16) _Float16 sB[128 * 32];

    const int tid = threadIdx.x;
    const int wid = tid >> 6, lane = tid & 63;
    const int wr = wid >> 1, wc = wid & 1;
    const int m0 = blockIdx.y * 128, n0 = blockIdx.x * 128;

    f32x4 acc[4][4];
    #pragma unroll
    for (int i = 0; i < 4; ++i)
        #pragma unroll
        for (int j = 0; j < 4; ++j)
            acc[i][j] = (f32x4){0.f, 0.f, 0.f, 0.f};

    // staging: wid0/1 -> A halves, wid2/3 -> B halves (4 loads each)
    const _Float16* gsrc = (wid < 2) ? A : B;
    _Float16* sdst = (wid < 2) ? sA : sB;
    const int gbase = (wid < 2) ? m0 : n0;
    const int ibase = (wid & 1) * 4;
    const int grow = gbase + (lane >> 2);
    const int gcol = (lane & 3) * 8;

    const int arow = wr * 64 + (lane & 15);
    const int brow = wc * 64 + (lane & 15);
    const int koff = (lane >> 4) * 8;

    for (int k0 = 0; k0 < CH; k0 += 32) {
        #pragma unroll
        for (int i = 0; i < 4; ++i) {
            const _Float16* g = gsrc + (size_t)(grow + (ibase + i) * 16) * CH + k0 + gcol;
            __builtin_amdgcn_global_load_lds((gvoid_t*)g,
                                             (lvoid_t*)(sdst + (ibase + i) * 512),
                                             16, 0, 0);
        }
        __syncthreads();

        f16x8 a[4], b[4];
        #pragma unroll
        for (int f = 0; f < 4; ++f) {
            a[f] = *(const f16x8*)&sA[(arow + f * 16) * 32 + koff];
            b[f] = *(const f16x8*)&sB[(brow + f * 16) * 32 + koff];
        }
        #pragma unroll
        for (int i = 0; i < 4; ++i)
            #pragma unroll
            for (int j = 0; j < 4; ++j)
                acc[i][j] = __builtin_amdgcn_mfma_f32_16x16x32_f16(a[i], b[j], acc[i][j], 0, 0, 0);
        __syncthreads();
    }

    const int crow = (lane >> 4) * 4;
    const int ccol = lane & 15;

    if (EPI == 1) {
        #pragma unroll
        for (int i = 0; i < 4; ++i) {
            #pragma unroll
            for (int j = 0; j < 4; ++j) {
                const int n = n0 + wc * 64 + j * 16 + ccol;
                const float bv = bias[n];
                #pragma unroll
                for (int r = 0; r < 4; ++r) {
                    const int m = m0 + wr * 64 + i * 16 + crow + r;
                    outp[(size_t)m * CH + n] = acc[i][j][r] + bv;
                }
            }
        }
    } else {
        const int nblk = n0 + wc * 64;
        const int sec = nblk >> 10;           // 0=q 1=k 2=v
        const int h = (nblk & 1023) >> 6;
        float bv[4];
        #pragma unroll
        for (int j = 0; j < 4; ++j) bv[j] = bias[nblk + j * 16 + ccol];

        if (sec < 2) {
            const float* gp = (sec == 0) ? qg : kg;
            const float* bp = (sec == 0) ? qb_ : kb_;
            float g4[4], b4[4];
            #pragma unroll
            for (int j = 0; j < 4; ++j) { g4[j] = gp[j*16+ccol]; b4[j] = bp[j*16+ccol]; }
            const float scale = (sec == 0) ? 0.125f : 1.0f;
            _Float16* dst = (sec == 0) ? qf : kf;
            #pragma unroll
            for (int i = 0; i < 4; ++i) {
                #pragma unroll
                for (int r = 0; r < 4; ++r) {
                    const int m = m0 + wr * 64 + i * 16 + crow + r;
                    const int b_ = m >> 10, nn = m & 1023;
                    float vals[4], s = 0.f, q2 = 0.f;
                    #pragma unroll
                    for (int j = 0; j < 4; ++j) {
                        vals[j] = acc[i][j][r] + bv[j];
                        s += vals[j]; q2 += vals[j] * vals[j];
                    }
                    #pragma unroll
                    for (int o = 1; o < 16; o <<= 1) {
                        s  += __shfl_xor(s, o, 64);
                        q2 += __shfl_xor(q2, o, 64);
                    }
                    const float mean = s * 0.015625f;
                    const float var = q2 * 0.015625f - mean * mean;
                    const float rstd = rsqrtf(var + 1e-5f);
                    #pragma unroll
                    for (int j = 0; j < 4; ++j) {
                        const float y = ((vals[j] - mean) * rstd * g4[j] + b4[j]) * scale;
                        dst[((size_t)(b_ * NH + h) * SQ + nn) * HD + j * 16 + ccol] = (_Float16)y;
                    }
                }
            }
        } else {
            #pragma unroll
            for (int i = 0; i < 4; ++i) {
                const int m0r = m0 + wr * 64 + i * 16 + crow;
                const int b_ = m0r >> 10, nn0 = m0r & 1023;
                #pragma unroll
                for (int j = 0; j < 4; ++j) {
                    f16x4 tmp;
                    #pragma unroll
                    for (int r = 0; r < 4; ++r) tmp[r] = (_Float16)(acc[i][j][r] + bv[j]);
                    *(f16x4*)&vTf[((size_t)(b_ * NH + h) * HD + j * 16 + ccol) * SQ + nn0] = tmp;
                }
            }
        }
    }
}

// ---------- fused QK^T + softmax(no-max: |logit|<=8 rigorous) + weights + PV ----------
// R12 core (512 blocks, 32 q-rows/wave, swapped QK^T, plain f32x4 W stores,
// XCD clustering, V loads before stores). Epilogue emits attention output as
// fp16 [B,N,C] via LDS transpose (proj GEMM consumes fp16 directly).
__global__ __launch_bounds__(256) void k_attn(
    const _Float16* __restrict__ q, const _Float16* __restrict__ k,
    const _Float16* __restrict__ vT, float* __restrict__ W,
    _Float16* __restrict__ opf)
{
    __shared__ _Float16 Pl[4][32][40];   // padded rows (80B): no 8-way conflicts
    __shared__ float Of[4][32][72];      // epilogue transpose (wave-private)
    const int L = blockIdx.x;            // 512 blocks
    const int bh   = (L & 7) * 8 + (L >> 6);
    const int xblk = (L >> 3) & 7;
    const int wid = threadIdx.x >> 6, lane = threadIdx.x & 63;
    const int row0 = xblk * 128 + wid * 32;   // this wave's 32 q-rows
    const int lr = lane & 15, lg = lane >> 4;

    const _Float16* qh = q  + (size_t)bh * SQ * HD;
    const _Float16* kh = k  + (size_t)bh * SQ * HD;
    const _Float16* vh = vT + (size_t)bh * HD * SQ;

    f16x8 qb[2][2];
    #pragma unroll
    for (int qf = 0; qf < 2; ++qf)
        #pragma unroll
        for (int c = 0; c < 2; ++c)
            qb[qf][c] = *(const f16x8*)&qh[(size_t)(row0 + qf * 16 + lr) * HD + c * 32 + lg * 8];

    // ---- phase 1: per-q row sums of exp(s) ----
    float lp0 = 0.f, lp1 = 0.f;
    #pragma unroll 4
    for (int kt = 0; kt < 64; ++kt) {
        const f16x8 ka0 = *(const f16x8*)&kh[(size_t)(kt * 16 + lr) * HD + lg * 8];
        const f16x8 ka1 = *(const f16x8*)&kh[(size_t)(kt * 16 + lr) * HD + 32 + lg * 8];
        f32x4 s0 = (f32x4){0.f, 0.f, 0.f, 0.f};
        f32x4 s1 = (f32x4){0.f, 0.f, 0.f, 0.f};
        s0 = __builtin_amdgcn_mfma_f32_16x16x32_f16(ka0, qb[0][0], s0, 0, 0, 0);
        s0 = __builtin_amdgcn_mfma_f32_16x16x32_f16(ka1, qb[0][1], s0, 0, 0, 0);
        s1 = __builtin_amdgcn_mfma_f32_16x16x32_f16(ka0, qb[1][0], s1, 0, 0, 0);
        s1 = __builtin_amdgcn_mfma_f32_16x16x32_f16(ka1, qb[1][1], s1, 0, 0, 0);
        #pragma unroll
        for (int r = 0; r < 4; ++r) { lp0 += __expf(s0[r]); lp1 += __expf(s1[r]); }
    }
    lp0 += __shfl_xor(lp0, 16, 64); lp0 += __shfl_xor(lp0, 32, 64);
    lp1 += __shfl_xor(lp1, 16, 64); lp1 += __shfl_xor(lp1, 32, 64);
    const float invl0 = 1.0f / lp0;      // q = row0 + lr
    const float invl1 = 1.0f / lp1;      // q = row0 + 16 + lr

    // ---- phase 2: recompute s, write weights (plain f32x4), PV ----
    float* Wr = W + (size_t)bh * SQ * SQ;
    f32x4 opv[4][2];
    #pragma unroll
    for (int dt = 0; dt < 4; ++dt)
        #pragma unroll
        for (int qf = 0; qf < 2; ++qf)
            opv[dt][qf] = (f32x4){0.f, 0.f, 0.f, 0.f};

    for (int jc = 0; jc < 32; ++jc) {          // 32-k chunks
        // V loads first — independent of P, free to fly early
        f16x8 vb[4];
        #pragma unroll
        for (int dt = 0; dt < 4; ++dt)
            vb[dt] = *(const f16x8*)&vh[(size_t)(dt * 16 + lr) * SQ + jc * 32 + lg * 8];

        #pragma unroll
        for (int t = 0; t < 2; ++t) {
            const int kt = jc * 2 + t;
            const f16x8 ka0 = *(const f16x8*)&kh[(size_t)(kt * 16 + lr) * HD + lg * 8];
            const f16x8 ka1 = *(const f16x8*)&kh[(size_t)(kt * 16 + lr) * HD + 32 + lg * 8];
            f32x4 s0 = (f32x4){0.f, 0.f, 0.f, 0.f};
            f32x4 s1 = (f32x4){0.f, 0.f, 0.f, 0.f};
            s0 = __builtin_amdgcn_mfma_f32_16x16x32_f16(ka0, qb[0][0], s0, 0, 0, 0);
            s0 = __builtin_amdgcn_mfma_f32_16x16x32_f16(ka1, qb[0][1], s0, 0, 0, 0);
            s1 = __builtin_amdgcn_mfma_f32_16x16x32_f16(ka0, qb[1][0], s1, 0, 0, 0);
            s1 = __builtin_amdgcn_mfma_f32_16x16x32_f16(ka1, qb[1][1], s1, 0, 0, 0);
            f32x4 wv0, wv1;
            f16x4 pv0, pv1;
            #pragma unroll
            for (int r = 0; r < 4; ++r) {
                wv0[r] = __expf(s0[r]) * invl0;  pv0[r] = (_Float16)wv0[r];
                wv1[r] = __expf(s1[r]) * invl1;  pv1[r] = (_Float16)wv1[r];
            }
            *(f32x4*)&Wr[(size_t)(row0 + lr) * SQ + kt * 16 + lg * 4]      = wv0;
            *(f32x4*)&Wr[(size_t)(row0 + 16 + lr) * SQ + kt * 16 + lg * 4] = wv1;
            *(f16x4*)&Pl[wid][lr][t * 16 + lg * 4]      = pv0;
            *(f16x4*)&Pl[wid][16 + lr][t * 16 + lg * 4] = pv1;
        }
        const f16x8 pa0 = *(const f16x8*)&Pl[wid][lr][lg * 8];
        const f16x8 pa1 = *(const f16x8*)&Pl[wid][16 + lr][lg * 8];
        #pragma unroll
        for (int dt = 0; dt < 4; ++dt) {
            opv[dt][0] = __builtin_amdgcn_mfma_f32_16x16x32_f16(pa0, vb[dt], opv[dt][0], 0, 0, 0);
            opv[dt][1] = __builtin_amdgcn_mfma_f32_16x16x32_f16(pa1, vb[dt], opv[dt][1], 0, 0, 0);
        }
    }

    // ---- epilogue: LDS transpose -> row-major fp16 [B,N,C] ----
    #pragma unroll
    for (int dt = 0; dt < 4; ++dt)
        #pragma unroll
        for (int qf = 0; qf < 2; ++qf)
            #pragma unroll
            for (int r = 0; r < 4; ++r)
                Of[wid][qf * 16 + lg * 4 + r][dt * 16 + lr] = opv[dt][qf][r];
    // wave-private buffer: compiler inserts lgkmcnt waits; no barrier needed
    const int b_ = bh >> 4, h = bh & 15;
    #pragma unroll
    for (int p = 0; p < 4; ++p) {
        const int r = p * 8 + (lane >> 3);
        const int c = (lane & 7) * 8;
        f16x8 hv;
        #pragma unroll
        for (int j = 0; j < 8; ++j)
            hv[j] = (_Float16)Of[wid][r][c + j];
        *(f16x8*)&opf[((size_t)(b_ * SQ + row0 + r)) * CH + h * HD + c] = hv;
    }
}

extern "C" void kernel_launch(void* const* d_in, const int* in_sizes, int n_in,
                              void* d_out, int out_size, void* d_ws, size_t ws_size,
                              hipStream_t stream)
{
    const float* x    = (const float*)d_in[0];
    const float* Wqkv = (const float*)d_in[1];
    const float* bqkv = (const float*)d_in[2];
    const float* qg   = (const float*)d_in[3];
    const float* qb   = (const float*)d_in[4];
    const float* kg   = (const float*)d_in[5];
    const float* kb   = (const float*)d_in[6];
    const float* Wp   = (const float*)d_in[7];
    const float* bp   = (const float*)d_in[8];

    float* out     = (float*)d_out;                       // [B,N,C]
    float* weights = out + (size_t)NB * SQ * CH;          // [B,H,N,N]

    // ws layout (MB): xf 0-8, wqf 8-14, wpf 14-16, qf 16-24, kf 24-32,
    //                 vT 32-40, opf 40-48
    char* w = (char*)d_ws;
    _Float16* xf  = (_Float16*)w;
    _Float16* wqf = (_Float16*)(w + (((size_t)8)  << 20));
    _Float16* wpf = (_Float16*)(w + (((size_t)14) << 20));
    _Float16* qf  = (_Float16*)(w + (((size_t)16) << 20));
    _Float16* kf  = (_Float16*)(w + (((size_t)24) << 20));
    _Float16* vTf = (_Float16*)(w + (((size_t)32) << 20));
    _Float16* opf = (_Float16*)(w + (((size_t)40) << 20));

    // 0) one-pass fp32 -> fp16 conversion of x, Wqkv, Wp
    k_split_all<<<dim3((NQ_X + NQ_WQ + NQ_WP) / 256), 256, 0, stream>>>(
        x, Wqkv, Wp, xf, wqf, wpf);

    // 1) qkv GEMM (fp16 single-pass) + fused bias+LN -> q,k fp16, vT fp16
    k_mfma_gemm<0><<<dim3(24, 32), 256, 0, stream>>>(
        xf, wqf, bqkv, nullptr, qf, kf, vTf, qg, qb, kg, kb);

    // 2) fused attention: QK^T + exact softmax + weights + PV -> fp16 out
    k_attn<<<dim3(512), 256, 0, stream>>>(qf, kf, vTf, weights, opf);

    // 3) proj GEMM (fp16 single-pass)
    k_mfma_gemm<1><<<dim3(8, 32), 256, 0, stream>>>(
        opf, wpf, bp, out, nullptr, nullptr, nullptr,
        nullptr, nullptr, nullptr, nullptr);
}